// Round 1
// baseline (531.292 us; speedup 1.0000x reference)
//
#include <hip/hip_runtime.h>
#include <math.h>

#define NB 4
#define NN 4096
#define NC 512
#define NF 64

// ---------------------------------------------------------------------------
// Kernel 1: fused 1x1-conv projections.  out[M][64] = x[M][512] @ W[512][64] + b
// grid (M/64, 3) ; block 256.  blockIdx.y selects {theta, phi, g}.
// ---------------------------------------------------------------------------
__global__ __launch_bounds__(256) void proj_kernel(
    const float* __restrict__ x,
    const float* __restrict__ Wt, const float* __restrict__ bt,
    const float* __restrict__ Wp, const float* __restrict__ bp,
    const float* __restrict__ Wg, const float* __restrict__ bg,
    float* __restrict__ theta, float* __restrict__ phi, float* __restrict__ g)
{
    const float* W; const float* bias; float* out;
    if (blockIdx.y == 0)      { W = Wt; bias = bt; out = theta; }
    else if (blockIdx.y == 1) { W = Wp; bias = bp; out = phi;   }
    else                      { W = Wg; bias = bg; out = g;     }

    __shared__ float xs[32][68];   // x tile, transposed: [k][r] (pad 68 for write banks)
    __shared__ float wsm[32][64];  // W tile: [k][c]

    const int tid  = threadIdx.x;
    const int row0 = blockIdx.x * 64;
    const int r0 = (tid >> 4) << 2;   // 0..60
    const int c0 = (tid & 15) << 2;   // 0..60

    const int sr  = tid >> 2;         // 0..63  (staging row)
    const int skq = (tid & 3) << 3;   // 0,8,16,24

    const int wk = tid >> 3;          // 0..31
    const int wc = (tid & 7) << 3;    // 0..56

    float acc[4][4] = {};

    for (int k0 = 0; k0 < NC; k0 += 32) {
        // stage x tile 64r x 32k (transposed into LDS)
        #pragma unroll
        for (int it = 0; it < 2; ++it) {
            float4 v = *reinterpret_cast<const float4*>(
                &x[(size_t)(row0 + sr) * NC + k0 + skq + 4 * it]);
            xs[skq + 4*it + 0][sr] = v.x;
            xs[skq + 4*it + 1][sr] = v.y;
            xs[skq + 4*it + 2][sr] = v.z;
            xs[skq + 4*it + 3][sr] = v.w;
        }
        // stage W tile 32k x 64c
        #pragma unroll
        for (int it = 0; it < 2; ++it) {
            float4 v = *reinterpret_cast<const float4*>(
                &W[(size_t)(k0 + wk) * NF + wc + 4 * it]);
            *reinterpret_cast<float4*>(&wsm[wk][wc + 4 * it]) = v;
        }
        __syncthreads();
        #pragma unroll
        for (int k = 0; k < 32; ++k) {
            const float4 a  = *reinterpret_cast<const float4*>(&xs[k][r0]);
            const float4 bq = *reinterpret_cast<const float4*>(&wsm[k][c0]);
            const float av[4] = {a.x, a.y, a.z, a.w};
            const float bv[4] = {bq.x, bq.y, bq.z, bq.w};
            #pragma unroll
            for (int i = 0; i < 4; ++i)
                #pragma unroll
                for (int jj = 0; jj < 4; ++jj)
                    acc[i][jj] = fmaf(av[i], bv[jj], acc[i][jj]);
        }
        __syncthreads();
    }

    const float4 bb = *reinterpret_cast<const float4*>(&bias[c0]);
    #pragma unroll
    for (int i = 0; i < 4; ++i) {
        float4 o;
        o.x = acc[i][0] + bb.x;
        o.y = acc[i][1] + bb.y;
        o.z = acc[i][2] + bb.z;
        o.w = acc[i][3] + bb.w;
        *reinterpret_cast<float4*>(&out[(size_t)(row0 + r0 + i) * NF + c0]) = o;
    }
}

// ---------------------------------------------------------------------------
// Kernel 2: flash attention, fp32.  grid (N/64, B); block 256 (4 waves).
// Per block: 64 query rows; loop over 64 K/V tiles of 64 with online softmax.
// attn_out[b][n][f] = softmax(theta phi^T) @ g
// ---------------------------------------------------------------------------
__global__ __launch_bounds__(256) void flash_kernel(
    const float* __restrict__ theta, const float* __restrict__ phi,
    const float* __restrict__ g, float* __restrict__ attn_out)
{
    __shared__ float thT[64 * 64]; // theta tile transposed: [f][r]
    __shared__ float phT[64 * 64]; // phi tile transposed:   [f][c]
    __shared__ float gs [64 * 64]; // g tile natural:        [c][f]
    __shared__ float ps [64 * 64]; // P tile natural:        [r][c]

    const int tid  = threadIdx.x;
    const int bb   = blockIdx.y;
    const int row0 = blockIdx.x * 64;
    const size_t base = (size_t)bb * NN * NF;

    const int sr = tid >> 2;         // 0..63
    const int sf = (tid & 3) << 4;   // 0,16,32,48

    // stage theta tile transposed (once)
    #pragma unroll
    for (int it = 0; it < 4; ++it) {
        float4 v = *reinterpret_cast<const float4*>(
            &theta[base + (size_t)(row0 + sr) * NF + sf + 4 * it]);
        thT[(sf + 4*it + 0) * 64 + sr] = v.x;
        thT[(sf + 4*it + 1) * 64 + sr] = v.y;
        thT[(sf + 4*it + 2) * 64 + sr] = v.z;
        thT[(sf + 4*it + 3) * 64 + sr] = v.w;
    }

    const int r0 = (tid >> 4) << 2;  // 4 query rows per thread (16 lane-group = 1 row-set)
    const int c0 = (tid & 15) << 2;  // 4 cols per thread; also the f-cols in PV

    float O[4][4] = {};
    float m_run[4], l_run[4];
    #pragma unroll
    for (int i = 0; i < 4; ++i) { m_run[i] = -INFINITY; l_run[i] = 0.0f; }

    __syncthreads();  // thT visible

    for (int j = 0; j < NN / 64; ++j) {
        // stage phi (transposed) + g (natural) tiles
        const size_t kb = base + (size_t)(j * 64 + sr) * NF;
        #pragma unroll
        for (int it = 0; it < 4; ++it) {
            float4 v = *reinterpret_cast<const float4*>(&phi[kb + sf + 4 * it]);
            phT[(sf + 4*it + 0) * 64 + sr] = v.x;
            phT[(sf + 4*it + 1) * 64 + sr] = v.y;
            phT[(sf + 4*it + 2) * 64 + sr] = v.z;
            phT[(sf + 4*it + 3) * 64 + sr] = v.w;
            float4 w = *reinterpret_cast<const float4*>(&g[kb + sf + 4 * it]);
            *reinterpret_cast<float4*>(&gs[sr * 64 + sf + 4 * it]) = w;
        }
        __syncthreads();

        // ---- scores tile: s[r][c] = sum_f theta[r][f] * phi[c][f] ----
        float s[4][4] = {};
        #pragma unroll
        for (int k = 0; k < 64; ++k) {
            const float4 a  = *reinterpret_cast<const float4*>(&thT[k * 64 + r0]);
            const float4 bq = *reinterpret_cast<const float4*>(&phT[k * 64 + c0]);
            const float av[4] = {a.x, a.y, a.z, a.w};
            const float bv[4] = {bq.x, bq.y, bq.z, bq.w};
            #pragma unroll
            for (int i = 0; i < 4; ++i)
                #pragma unroll
                for (int jj = 0; jj < 4; ++jj)
                    s[i][jj] = fmaf(av[i], bv[jj], s[i][jj]);
        }

        // ---- online softmax (row stats across the 16-lane row group) ----
        #pragma unroll
        for (int i = 0; i < 4; ++i) {
            float mx = fmaxf(fmaxf(s[i][0], s[i][1]), fmaxf(s[i][2], s[i][3]));
            #pragma unroll
            for (int msk = 1; msk <= 8; msk <<= 1)
                mx = fmaxf(mx, __shfl_xor(mx, msk, 64));
            const float mn = fmaxf(m_run[i], mx);
            const float sc = __expf(m_run[i] - mn);
            m_run[i] = mn;
            float psum = 0.0f;
            #pragma unroll
            for (int jj = 0; jj < 4; ++jj) {
                s[i][jj] = __expf(s[i][jj] - mn);
                psum += s[i][jj];
            }
            #pragma unroll
            for (int msk = 1; msk <= 8; msk <<= 1)
                psum += __shfl_xor(psum, msk, 64);
            l_run[i] = l_run[i] * sc + psum;
            #pragma unroll
            for (int jj = 0; jj < 4; ++jj) O[i][jj] *= sc;
        }

        // write P tile (natural layout, one float4 per row)
        #pragma unroll
        for (int i = 0; i < 4; ++i) {
            float4 p;
            p.x = s[i][0]; p.y = s[i][1]; p.z = s[i][2]; p.w = s[i][3];
            *reinterpret_cast<float4*>(&ps[(r0 + i) * 64 + c0]) = p;
        }
        __syncthreads();

        // ---- PV: O[r][f] += sum_c P[r][c] * g[c][f]   (f-cols == c0) ----
        #pragma unroll
        for (int k0 = 0; k0 < 64; k0 += 4) {
            float av[4][4];
            #pragma unroll
            for (int i = 0; i < 4; ++i) {
                const float4 t = *reinterpret_cast<const float4*>(&ps[(r0 + i) * 64 + k0]);
                av[i][0] = t.x; av[i][1] = t.y; av[i][2] = t.z; av[i][3] = t.w;
            }
            #pragma unroll
            for (int kk = 0; kk < 4; ++kk) {
                const float4 bq = *reinterpret_cast<const float4*>(&gs[(k0 + kk) * 64 + c0]);
                const float bv[4] = {bq.x, bq.y, bq.z, bq.w};
                #pragma unroll
                for (int i = 0; i < 4; ++i)
                    #pragma unroll
                    for (int jj = 0; jj < 4; ++jj)
                        O[i][jj] = fmaf(av[i][kk], bv[jj], O[i][jj]);
            }
        }
        __syncthreads();
    }

    // finalize: divide by l, store
    #pragma unroll
    for (int i = 0; i < 4; ++i) {
        const float inv = 1.0f / l_run[i];
        float4 o;
        o.x = O[i][0] * inv; o.y = O[i][1] * inv;
        o.z = O[i][2] * inv; o.w = O[i][3] * inv;
        *reinterpret_cast<float4*>(&attn_out[base + (size_t)(row0 + r0 + i) * NF + c0]) = o;
    }
}

// ---------------------------------------------------------------------------
// Kernel 3: out = x + (attn_out @ W_out + b_out).  grid (M/64, C/128); block 256.
// ---------------------------------------------------------------------------
__global__ __launch_bounds__(256) void outproj_kernel(
    const float* __restrict__ attn, const float* __restrict__ Wo,
    const float* __restrict__ bo, const float* __restrict__ x,
    float* __restrict__ out)
{
    __shared__ float aT[64 * 64];   // attn tile transposed [k][r]
    __shared__ float wt[64][128];   // W_out tile [k][c]

    const int tid  = threadIdx.x;
    const int row0 = blockIdx.x * 64;
    const int cblk = blockIdx.y * 128;

    // stage attn tile transposed
    const int sr = tid >> 2;         // 0..63
    const int sf = (tid & 3) << 4;   // 0,16,32,48
    #pragma unroll
    for (int it = 0; it < 4; ++it) {
        float4 v = *reinterpret_cast<const float4*>(
            &attn[(size_t)(row0 + sr) * NF + sf + 4 * it]);
        aT[(sf + 4*it + 0) * 64 + sr] = v.x;
        aT[(sf + 4*it + 1) * 64 + sr] = v.y;
        aT[(sf + 4*it + 2) * 64 + sr] = v.z;
        aT[(sf + 4*it + 3) * 64 + sr] = v.w;
    }
    // stage W_out tile 64k x 128c
    {
        const int wk = tid >> 2;          // 0..63
        const int wc = (tid & 3) << 5;    // 0,32,64,96
        #pragma unroll
        for (int it = 0; it < 8; ++it) {
            float4 v = *reinterpret_cast<const float4*>(
                &Wo[(size_t)wk * NC + cblk + wc + 4 * it]);
            *reinterpret_cast<float4*>(&wt[wk][wc + 4 * it]) = v;
        }
    }
    __syncthreads();

    const int r0 = (tid >> 5) << 3;   // 0..56 (8 rows / thread)
    const int c0 = (tid & 31) << 2;   // 0..124 (4 cols / thread)

    float acc[8][4] = {};
    #pragma unroll
    for (int k = 0; k < 64; ++k) {
        const float4 w4  = *reinterpret_cast<const float4*>(&wt[k][c0]);
        const float4 alo = *reinterpret_cast<const float4*>(&aT[k * 64 + r0]);
        const float4 ahi = *reinterpret_cast<const float4*>(&aT[k * 64 + r0 + 4]);
        const float av[8] = {alo.x, alo.y, alo.z, alo.w, ahi.x, ahi.y, ahi.z, ahi.w};
        const float wv[4] = {w4.x, w4.y, w4.z, w4.w};
        #pragma unroll
        for (int i = 0; i < 8; ++i)
            #pragma unroll
            for (int jj = 0; jj < 4; ++jj)
                acc[i][jj] = fmaf(av[i], wv[jj], acc[i][jj]);
    }

    const float4 bq = *reinterpret_cast<const float4*>(&bo[cblk + c0]);
    #pragma unroll
    for (int i = 0; i < 8; ++i) {
        const size_t idx = (size_t)(row0 + r0 + i) * NC + cblk + c0;
        const float4 xv = *reinterpret_cast<const float4*>(&x[idx]);
        float4 o;
        o.x = acc[i][0] + bq.x + xv.x;
        o.y = acc[i][1] + bq.y + xv.y;
        o.z = acc[i][2] + bq.z + xv.z;
        o.w = acc[i][3] + bq.w + xv.w;
        *reinterpret_cast<float4*>(&out[idx]) = o;
    }
}

// ---------------------------------------------------------------------------
extern "C" void kernel_launch(void* const* d_in, const int* in_sizes, int n_in,
                              void* d_out, int out_size, void* d_ws, size_t ws_size,
                              hipStream_t stream) {
    const float* x  = (const float*)d_in[0];
    const float* Wt = (const float*)d_in[1];
    const float* bt = (const float*)d_in[2];
    const float* Wp = (const float*)d_in[3];
    const float* bp = (const float*)d_in[4];
    const float* Wg = (const float*)d_in[5];
    const float* bg = (const float*)d_in[6];
    const float* Wo = (const float*)d_in[7];
    const float* bo = (const float*)d_in[8];
    float* out = (float*)d_out;

    const size_t per = (size_t)NB * NN * NF;   // 1,048,576 floats each
    float* theta = (float*)d_ws;
    float* phi   = theta + per;
    float* g     = phi + per;
    float* attn  = g + per;

    const int M = NB * NN;  // 16384

    proj_kernel<<<dim3(M / 64, 3), 256, 0, stream>>>(
        x, Wt, bt, Wp, bp, Wg, bg, theta, phi, g);
    flash_kernel<<<dim3(NN / 64, NB), 256, 0, stream>>>(theta, phi, g, attn);
    outproj_kernel<<<dim3(M / 64, NC / 128), 256, 0, stream>>>(attn, Wo, bo, x, out);
}

// Round 3
// 241.550 us; speedup vs baseline: 2.1995x; 2.1995x over previous
//
#include <hip/hip_runtime.h>
#include <math.h>

#define NB 4
#define NN 4096
#define NC 512
#define NF 64

typedef __attribute__((ext_vector_type(8))) short short8;
typedef __attribute__((ext_vector_type(4))) float f32x4;

#define MFMA16(a, b, c) __builtin_amdgcn_mfma_f32_16x16x32_bf16(a, b, c, 0, 0, 0)

static __device__ inline unsigned short f2bf(float f) {
    unsigned u = __float_as_uint(f);
    u = (u + 0x7FFFu + ((u >> 16) & 1u)) >> 16;
    return (unsigned short)u;
}
static __device__ inline float bf2f(unsigned short h) {
    return __uint_as_float(((unsigned)h) << 16);
}

// ---------------------------------------------------------------------------
// Kernel 1: fused projections. theta/phi emitted as bf16 hi+lo split pairs
// (for bf16x3 MFMA QK^T), g emitted transposed bf16 gT[b][f][n] (PV B-operand).
// grid (M/64, 3); block 256.
// ---------------------------------------------------------------------------
__global__ __launch_bounds__(256) void proj_kernel(
    const float* __restrict__ x,
    const float* __restrict__ Wt, const float* __restrict__ bt,
    const float* __restrict__ Wp, const float* __restrict__ bp,
    const float* __restrict__ Wg, const float* __restrict__ bg,
    unsigned short* __restrict__ th_hi, unsigned short* __restrict__ th_lo,
    unsigned short* __restrict__ ph_hi, unsigned short* __restrict__ ph_lo,
    unsigned short* __restrict__ gT)
{
    const float* W; const float* bias;
    unsigned short* hi_arr; unsigned short* lo_arr;
    if (blockIdx.y == 0)      { W = Wt; bias = bt; hi_arr = th_hi; lo_arr = th_lo; }
    else if (blockIdx.y == 1) { W = Wp; bias = bp; hi_arr = ph_hi; lo_arr = ph_lo; }
    else                      { W = Wg; bias = bg; hi_arr = 0;     lo_arr = 0;     }

    __shared__ float xs[32][68];   // x tile transposed [k][r], padded
    __shared__ float wsm[32][64];  // W tile [k][c]

    const int tid  = threadIdx.x;
    const int row0 = blockIdx.x * 64;
    const int r0 = (tid >> 4) << 2;
    const int c0 = (tid & 15) << 2;

    const int sr  = tid >> 2;
    const int skq = (tid & 3) << 3;

    const int wk = tid >> 3;
    const int wc = (tid & 7) << 3;

    float acc[4][4] = {};

    for (int k0 = 0; k0 < NC; k0 += 32) {
        #pragma unroll
        for (int it = 0; it < 2; ++it) {
            float4 v = *reinterpret_cast<const float4*>(
                &x[(size_t)(row0 + sr) * NC + k0 + skq + 4 * it]);
            xs[skq + 4*it + 0][sr] = v.x;
            xs[skq + 4*it + 1][sr] = v.y;
            xs[skq + 4*it + 2][sr] = v.z;
            xs[skq + 4*it + 3][sr] = v.w;
        }
        #pragma unroll
        for (int it = 0; it < 2; ++it) {
            float4 v = *reinterpret_cast<const float4*>(
                &W[(size_t)(k0 + wk) * NF + wc + 4 * it]);
            *reinterpret_cast<float4*>(&wsm[wk][wc + 4 * it]) = v;
        }
        __syncthreads();
        #pragma unroll
        for (int k = 0; k < 32; ++k) {
            const float4 a  = *reinterpret_cast<const float4*>(&xs[k][r0]);
            const float4 bq = *reinterpret_cast<const float4*>(&wsm[k][c0]);
            const float av[4] = {a.x, a.y, a.z, a.w};
            const float bv[4] = {bq.x, bq.y, bq.z, bq.w};
            #pragma unroll
            for (int i = 0; i < 4; ++i)
                #pragma unroll
                for (int jj = 0; jj < 4; ++jj)
                    acc[i][jj] = fmaf(av[i], bv[jj], acc[i][jj]);
        }
        __syncthreads();
    }

    const float4 bb = *reinterpret_cast<const float4*>(&bias[c0]);
    const float bbv[4] = {bb.x, bb.y, bb.z, bb.w};

    if (blockIdx.y < 2) {
        #pragma unroll
        for (int i = 0; i < 4; ++i) {
            const int m = row0 + r0 + i;
            ushort4 hq, lq;
            unsigned short h; float v;
            v = acc[i][0] + bbv[0]; h = f2bf(v); hq.x = h; lq.x = f2bf(v - bf2f(h));
            v = acc[i][1] + bbv[1]; h = f2bf(v); hq.y = h; lq.y = f2bf(v - bf2f(h));
            v = acc[i][2] + bbv[2]; h = f2bf(v); hq.z = h; lq.z = f2bf(v - bf2f(h));
            v = acc[i][3] + bbv[3]; h = f2bf(v); hq.w = h; lq.w = f2bf(v - bf2f(h));
            *reinterpret_cast<ushort4*>(&hi_arr[(size_t)m * NF + c0]) = hq;
            *reinterpret_cast<ushort4*>(&lo_arr[(size_t)m * NF + c0]) = lq;
        }
    } else {
        #pragma unroll
        for (int i = 0; i < 4; ++i) {
            const int m = row0 + r0 + i;
            const int bbi = m >> 12;
            const int n = m & (NN - 1);
            #pragma unroll
            for (int jj = 0; jj < 4; ++jj) {
                float v = acc[i][jj] + bbv[jj];
                gT[((size_t)bbi * NF + c0 + jj) * NN + n] = f2bf(v);
            }
        }
    }
}

// ---------------------------------------------------------------------------
// Kernel 2: flash attention via bf16 MFMA (bf16x3 split QK^T, plain-bf16 PV).
// grid (64, 4) remapped XCD-chunked; block 512 (8 waves).
// wave = (row band p = w&3) x (KV parity q = w>>2); split-K merge at end.
// LDS 64KB: 2 staged KV tiles (khi/klo/vT, XOR-swizzled) + 2KB P per wave.
// ---------------------------------------------------------------------------
__global__ __launch_bounds__(512, 1) void flash_kernel(
    const unsigned short* __restrict__ th_hi, const unsigned short* __restrict__ th_lo,
    const unsigned short* __restrict__ ph_hi, const unsigned short* __restrict__ ph_lo,
    const unsigned short* __restrict__ gT, float* __restrict__ attn)
{
    __shared__ __align__(16) char smem[65536];
    // bytes: tile s in {0,1}: base s*24576: khi +0, klo +8192, vT +16384
    // P: 49152 + wave*2048

    const int tid  = threadIdx.x;
    const int wv   = tid >> 6;
    const int lane = tid & 63;
    const int p    = wv & 3;      // row band
    const int q    = wv >> 2;     // KV parity
    const int l15  = lane & 15;
    const int g    = lane >> 4;   // 0..3

    // XCD-chunked block remap (bijective, 256 = 8*32)
    const int bid = blockIdx.y * 64 + blockIdx.x;
    const int wg  = (bid & 7) * 32 + (bid >> 3);
    const int qt  = wg & 63;
    const int bb  = wg >> 6;

    const int row0 = qt * 64;
    const size_t base = (size_t)bb * NN * NF;

    // ---- Q A-fragments straight from global into registers (held all kernel) ----
    short8 qhi[2], qlo[2];
    {
        const char* thp = (const char*)(th_hi + base) + (size_t)(row0 + p * 16 + l15) * 128 + g * 16;
        const char* tlp = (const char*)(th_lo + base) + (size_t)(row0 + p * 16 + l15) * 128 + g * 16;
        qhi[0] = *reinterpret_cast<const short8*>(thp);
        qhi[1] = *reinterpret_cast<const short8*>(thp + 64);
        qlo[0] = *reinterpret_cast<const short8*>(tlp);
        qlo[1] = *reinterpret_cast<const short8*>(tlp + 64);
    }

    f32x4 o[4];
    #pragma unroll
    for (int ff = 0; ff < 4; ++ff) o[ff] = (f32x4){0.f, 0.f, 0.f, 0.f};
    float m_run[4], l_run[4];
    #pragma unroll
    for (int reg = 0; reg < 4; ++reg) { m_run[reg] = -1e30f; l_run[reg] = 0.f; }

    const int r_st = tid >> 3;                 // staging row 0..63
    const int c_st = tid & 7;                  // 16B chunk 0..7
    const int swz_st = (r_st & 7) << 4;
    char* psb = smem + 49152 + wv * 2048;      // this wave's P buffer

    for (int t = 0; t < NN / 128; ++t) {
        // ---- stage KV tile pair 2t, 2t+1 (reg-staged, swizzled dest) ----
        #pragma unroll
        for (int s = 0; s < 2; ++s) {
            const int j = 2 * t + s;
            char* db = smem + s * 24576;
            const char* skh = (const char*)(ph_hi + base + (size_t)(j * 64 + r_st) * NF) + c_st * 16;
            const char* skl = (const char*)(ph_lo + base + (size_t)(j * 64 + r_st) * NF) + c_st * 16;
            const char* sv  = (const char*)(gT + ((size_t)bb * NF + r_st) * NN + j * 64) + c_st * 16;
            float4 vh = *reinterpret_cast<const float4*>(skh);
            float4 vl = *reinterpret_cast<const float4*>(skl);
            float4 vv = *reinterpret_cast<const float4*>(sv);
            const int doff = r_st * 128 + ((c_st * 16) ^ swz_st);
            *reinterpret_cast<float4*>(db + doff)         = vh;
            *reinterpret_cast<float4*>(db + 8192 + doff)  = vl;
            *reinterpret_cast<float4*>(db + 16384 + doff) = vv;
        }
        __syncthreads();

        // ---- this wave's tile: j = 2t + q, from buffer q ----
        const char* kb = smem + q * 24576;

        // QK^T (bf16x3 split): S frags cf=0..3, rows p*16+(4g+reg), col cf*16+l15
        f32x4 s_acc[4];
        #pragma unroll
        for (int cf = 0; cf < 4; ++cf) {
            s_acc[cf] = (f32x4){0.f, 0.f, 0.f, 0.f};
            const int r = cf * 16 + l15;            // K row (KV col)
            const char* rowp = kb + r * 128;
            const int swz = (r & 7) << 4;
            #pragma unroll
            for (int ks = 0; ks < 2; ++ks) {
                const int off = (ks * 64 + g * 16) ^ swz;
                short8 bh = *reinterpret_cast<const short8*>(rowp + off);
                short8 bl = *reinterpret_cast<const short8*>(rowp + 8192 + off);
                s_acc[cf] = MFMA16(qhi[ks], bh, s_acc[cf]);
                s_acc[cf] = MFMA16(qlo[ks], bh, s_acc[cf]);
                s_acc[cf] = MFMA16(qhi[ks], bl, s_acc[cf]);
            }
        }

        // ---- online softmax (rows fully within wave; 16-lane shfl reduce) ----
        float mnew[4], scl[4], psum[4];
        #pragma unroll
        for (int reg = 0; reg < 4; ++reg) {
            float mx = fmaxf(fmaxf(s_acc[0][reg], s_acc[1][reg]),
                             fmaxf(s_acc[2][reg], s_acc[3][reg]));
            mx = fmaxf(mx, __shfl_xor(mx, 1));
            mx = fmaxf(mx, __shfl_xor(mx, 2));
            mx = fmaxf(mx, __shfl_xor(mx, 4));
            mx = fmaxf(mx, __shfl_xor(mx, 8));
            mnew[reg] = fmaxf(m_run[reg], mx);
            scl[reg]  = __expf(m_run[reg] - mnew[reg]);
            m_run[reg] = mnew[reg];
            psum[reg] = 0.f;
        }
        #pragma unroll
        for (int cf = 0; cf < 4; ++cf) {
            #pragma unroll
            for (int reg = 0; reg < 4; ++reg) {
                float pe = __expf(s_acc[cf][reg] - mnew[reg]);
                psum[reg] += pe;
                const int r = 4 * g + reg;
                const int c = cf * 16 + l15;
                *reinterpret_cast<unsigned short*>(
                    psb + r * 128 + ((c * 2) ^ ((r & 7) << 4))) = f2bf(pe);
            }
        }
        #pragma unroll
        for (int reg = 0; reg < 4; ++reg) {
            float ss = psum[reg];
            ss += __shfl_xor(ss, 1);
            ss += __shfl_xor(ss, 2);
            ss += __shfl_xor(ss, 4);
            ss += __shfl_xor(ss, 8);
            l_run[reg] = l_run[reg] * scl[reg] + ss;
            o[0][reg] *= scl[reg];
            o[1][reg] *= scl[reg];
            o[2][reg] *= scl[reg];
            o[3][reg] *= scl[reg];
        }

        // P writes must land before same-wave P reads (cross-lane via LDS)
        asm volatile("s_waitcnt lgkmcnt(0)" ::: "memory");

        // ---- PV: O[r][f] += P[r][c] * g[c][f]  (A = P from LDS, B = vT) ----
        const char* vb = kb + 16384;
        #pragma unroll
        for (int ks = 0; ks < 2; ++ks) {
            const int pr = l15;
            short8 pa = *reinterpret_cast<const short8*>(
                psb + pr * 128 + (((ks * 64 + g * 16)) ^ ((pr & 7) << 4)));
            #pragma unroll
            for (int ff = 0; ff < 4; ++ff) {
                const int fr = ff * 16 + l15;
                short8 vvf = *reinterpret_cast<const short8*>(
                    vb + fr * 128 + ((ks * 64 + g * 16) ^ ((fr & 7) << 4)));
                o[ff] = MFMA16(pa, vvf, o[ff]);
            }
        }
        __syncthreads();
    }

    // ---- split-K merge of the q=0 / q=1 halves (reuse staging LDS) ----
    float* mO = (float*)smem;                 // [4 band][16][64]
    float* ml = (float*)(smem + 16384);       // [64][2]
    if (q == 1) {
        float* bo = mO + p * 1024;
        #pragma unroll
        for (int ff = 0; ff < 4; ++ff)
            #pragma unroll
            for (int reg = 0; reg < 4; ++reg)
                bo[(4 * g + reg) * 64 + ff * 16 + l15] = o[ff][reg];
        if (l15 == 0) {
            #pragma unroll
            for (int reg = 0; reg < 4; ++reg) {
                ml[(p * 16 + 4 * g + reg) * 2 + 0] = m_run[reg];
                ml[(p * 16 + 4 * g + reg) * 2 + 1] = l_run[reg];
            }
        }
    }
    __syncthreads();
    if (q == 0) {
        const float* bo = mO + p * 1024;
        #pragma unroll
        for (int reg = 0; reg < 4; ++reg) {
            const int r = 4 * g + reg;
            const float m1 = ml[(p * 16 + r) * 2 + 0];
            const float l1 = ml[(p * 16 + r) * 2 + 1];
            const float m  = fmaxf(m_run[reg], m1);
            const float a0 = __expf(m_run[reg] - m);
            const float a1 = __expf(m1 - m);
            const float inv = 1.0f / (a0 * l_run[reg] + a1 * l1);
            #pragma unroll
            for (int ff = 0; ff < 4; ++ff) {
                float val = (a0 * o[ff][reg] + a1 * bo[r * 64 + ff * 16 + l15]) * inv;
                attn[base + (size_t)(row0 + p * 16 + r) * NF + ff * 16 + l15] = val;
            }
        }
    }
}

// ---------------------------------------------------------------------------
// Kernel 3: out = x + (attn @ W_out + b_out).  grid (M/64, C/128); block 256.
// ---------------------------------------------------------------------------
__global__ __launch_bounds__(256) void outproj_kernel(
    const float* __restrict__ attn, const float* __restrict__ Wo,
    const float* __restrict__ bo, const float* __restrict__ x,
    float* __restrict__ out)
{
    __shared__ float aT[64 * 64];
    __shared__ float wt[64][128];

    const int tid  = threadIdx.x;
    const int row0 = blockIdx.x * 64;
    const int cblk = blockIdx.y * 128;

    const int sr = tid >> 2;
    const int sf = (tid & 3) << 4;
    #pragma unroll
    for (int it = 0; it < 4; ++it) {
        float4 v = *reinterpret_cast<const float4*>(
            &attn[(size_t)(row0 + sr) * NF + sf + 4 * it]);
        aT[(sf + 4*it + 0) * 64 + sr] = v.x;
        aT[(sf + 4*it + 1) * 64 + sr] = v.y;
        aT[(sf + 4*it + 2) * 64 + sr] = v.z;
        aT[(sf + 4*it + 3) * 64 + sr] = v.w;
    }
    {
        const int wk = tid >> 2;
        const int wc = (tid & 3) << 5;
        #pragma unroll
        for (int it = 0; it < 8; ++it) {
            float4 v = *reinterpret_cast<const float4*>(
                &Wo[(size_t)wk * NC + cblk + wc + 4 * it]);
            *reinterpret_cast<float4*>(&wt[wk][wc + 4 * it]) = v;
        }
    }
    __syncthreads();

    const int r0 = (tid >> 5) << 3;
    const int c0 = (tid & 31) << 2;

    float acc[8][4] = {};
    #pragma unroll
    for (int k = 0; k < 64; ++k) {
        const float4 w4  = *reinterpret_cast<const float4*>(&wt[k][c0]);
        const float4 alo = *reinterpret_cast<const float4*>(&aT[k * 64 + r0]);
        const float4 ahi = *reinterpret_cast<const float4*>(&aT[k * 64 + r0 + 4]);
        const float av[8] = {alo.x, alo.y, alo.z, alo.w, ahi.x, ahi.y, ahi.z, ahi.w};
        const float wv[4] = {w4.x, w4.y, w4.z, w4.w};
        #pragma unroll
        for (int i = 0; i < 8; ++i)
            #pragma unroll
            for (int jj = 0; jj < 4; ++jj)
                acc[i][jj] = fmaf(av[i], wv[jj], acc[i][jj]);
    }

    const float4 bq = *reinterpret_cast<const float4*>(&bo[cblk + c0]);
    #pragma unroll
    for (int i = 0; i < 8; ++i) {
        const size_t idx = (size_t)(row0 + r0 + i) * NC + cblk + c0;
        const float4 xv = *reinterpret_cast<const float4*>(&x[idx]);
        float4 ov;
        ov.x = acc[i][0] + bq.x + xv.x;
        ov.y = acc[i][1] + bq.y + xv.y;
        ov.z = acc[i][2] + bq.z + xv.z;
        ov.w = acc[i][3] + bq.w + xv.w;
        *reinterpret_cast<float4*>(&out[idx]) = ov;
    }
}

// ---------------------------------------------------------------------------
extern "C" void kernel_launch(void* const* d_in, const int* in_sizes, int n_in,
                              void* d_out, int out_size, void* d_ws, size_t ws_size,
                              hipStream_t stream) {
    const float* x  = (const float*)d_in[0];
    const float* Wt = (const float*)d_in[1];
    const float* bt = (const float*)d_in[2];
    const float* Wp = (const float*)d_in[3];
    const float* bp = (const float*)d_in[4];
    const float* Wg = (const float*)d_in[5];
    const float* bg = (const float*)d_in[6];
    const float* Wo = (const float*)d_in[7];
    const float* bo = (const float*)d_in[8];
    float* out = (float*)d_out;

    const size_t per = (size_t)NB * NN * NF;   // 1,048,576 elements
    unsigned short* th_hi = (unsigned short*)d_ws;
    unsigned short* th_lo = th_hi + per;
    unsigned short* ph_hi = th_lo + per;
    unsigned short* ph_lo = ph_hi + per;
    unsigned short* gTw   = ph_lo + per;
    float* attn = (float*)((char*)d_ws + 5 * per * sizeof(unsigned short));

    const int M = NB * NN;  // 16384

    proj_kernel<<<dim3(M / 64, 3), 256, 0, stream>>>(
        x, Wt, bt, Wp, bp, Wg, bg, th_hi, th_lo, ph_hi, ph_lo, gTw);
    flash_kernel<<<dim3(NN / 64, NB), 512, 0, stream>>>(
        th_hi, th_lo, ph_hi, ph_lo, gTw, attn);
    outproj_kernel<<<dim3(M / 64, NC / 128), 256, 0, stream>>>(attn, Wo, bo, x, out);
}